// Round 5
// baseline (191.838 us; speedup 1.0000x reference)
//
#include <hip/hip_runtime.h>
#include <cstdint>
#include <cstddef>

// ---------------------------------------------------------------------------
// RelativePositionMultiHeadAttention, B=4 L=1024 D=1024 H=16 dk=64
// Identity: BD[...,L-1:][b,h,i,j] = Q[b,h,i] . Er[4999-j]
//  => scores = Q @ (K + Er_flip)^T / 8  -> plain softmax attention.
// R5: gemm_qkv V-epilogue LDS transpose -> coalesced dwordx4 stores (was a
//     64-line/instr 4B scatter); wsel branch hoisted to block level.
// ---------------------------------------------------------------------------

typedef __attribute__((ext_vector_type(8))) short short8;   // 8 x bf16 (4 VGPR)
typedef __attribute__((ext_vector_type(4))) float f32x4;    // 4 x f32

#define MFMA_BF16(a, b, c) __builtin_amdgcn_mfma_f32_16x16x32_bf16((a), (b), (c), 0, 0, 0)

constexpr int kB = 4, kL = 1024, kD = 1024, kH = 16;
constexpr int kBL = kB * kL;   // 4096
constexpr float kScale = 0.125f * 1.44269504088896340736f;  // log2(e)/sqrt(dk)

static __device__ __forceinline__ unsigned short f32_to_bf16(float f) {
  union { float f; uint32_t u; } c; c.f = f;
  uint32_t u = c.u + 0x7fffu + ((c.u >> 16) & 1u);  // RNE
  return (unsigned short)(u >> 16);
}

static __device__ __forceinline__ void gload_lds16(const void* g, void* l) {
  __builtin_amdgcn_global_load_lds(
      (const __attribute__((address_space(1))) void*)g,
      (__attribute__((address_space(3))) void*)l, 16, 0, 0);
}

// ---------------- single fused cast: x, Wq, Wk, Wv, Wo -> bf16 ----------------
__global__ __launch_bounds__(256)
void cast_all(const float* __restrict__ x,  const float* __restrict__ Wq,
              const float* __restrict__ Wk, const float* __restrict__ Wv,
              const float* __restrict__ Wo,
              unsigned short* __restrict__ xb, unsigned short* __restrict__ Wcat,
              unsigned short* __restrict__ Wob) {
  int i = blockIdx.x * blockDim.x + threadIdx.x;
  const float* src;
  ushort4* dst;
  int off;
  if (i < 1048576) {
    src = x; dst = reinterpret_cast<ushort4*>(xb); off = i;
  } else {
    int j = i - 1048576;
    int seg = j >> 18;          // 0..3
    off = j & 262143;
    if (seg == 0)      { src = Wq; dst = reinterpret_cast<ushort4*>(Wcat); }
    else if (seg == 1) { src = Wk; dst = reinterpret_cast<ushort4*>(Wcat) + 262144; }
    else if (seg == 2) { src = Wv; dst = reinterpret_cast<ushort4*>(Wcat) + 524288; }
    else               { src = Wo; dst = reinterpret_cast<ushort4*>(Wob); }
  }
  float4 v = reinterpret_cast<const float4*>(src)[off];
  ushort4 o;
  o.x = f32_to_bf16(v.x); o.y = f32_to_bf16(v.y);
  o.z = f32_to_bf16(v.z); o.w = f32_to_bf16(v.w);
  dst[off] = o;
}

// ---------------- fused QKV GEMM  [4096 x 3072] = xb @ Wcat^T ----------------
// 128x128 tile, BK=32, 4 waves (2x2 of 64x64).  C/D: col=lane&15, row=quad*4+reg.
// LDS: 36 KB arena; As/Bs (8 KB each) during K-loop, reused as per-wave 64x72
// transpose tiles (9 KB x 4) for the V epilogue.
__global__ __launch_bounds__(256)
void gemm_qkv(const unsigned short* __restrict__ A,   // 4096 x 1024 bf16
              const unsigned short* __restrict__ Bm,  // 3072 x 1024 bf16
              const float* __restrict__ bq, const float* __restrict__ bk,
              const float* __restrict__ bv,
              const float* __restrict__ Er,           // 5000x64 f32
              unsigned short* __restrict__ Qh, unsigned short* __restrict__ Kh,
              unsigned short* __restrict__ Vth) {
  __shared__ __align__(16) char smem[36864];
  unsigned short* As = (unsigned short*)smem;          // 128*32
  unsigned short* Bs = (unsigned short*)(smem + 8192); // 128*32
  const int tid  = threadIdx.x;
  const int lane = tid & 63, wave = tid >> 6;
  const int quad = lane >> 4, l15 = lane & 15;
  const int m0 = blockIdx.y * 128, n0 = blockIdx.x * 128;
  const int wm = (wave >> 1) * 64, wn = (wave & 1) * 64;
  const int K = 1024;

  const f32x4 vzero = {0.f, 0.f, 0.f, 0.f};
  f32x4 acc[4][4];
#pragma unroll
  for (int i = 0; i < 4; ++i)
#pragma unroll
    for (int j = 0; j < 4; ++j) acc[i][j] = vzero;

  for (int k0 = 0; k0 < K; k0 += 32) {
    __syncthreads();
#pragma unroll
    for (int r = 0; r < 2; ++r) {
      int u = r * 256 + tid;            // 512 x 16B units per buffer
      int row = u >> 2, col = (u & 3) * 8;
      gload_lds16(A  + (size_t)(m0 + row) * K + k0 + col, (char*)As + (size_t)u * 16);
      gload_lds16(Bm + (size_t)(n0 + row) * K + k0 + col, (char*)Bs + (size_t)u * 16);
    }
    __syncthreads();

    short8 af[4], bfv[4];
#pragma unroll
    for (int mt = 0; mt < 4; ++mt)
      af[mt] = *(const short8*)&As[(wm + mt * 16 + l15) * 32 + quad * 8];
#pragma unroll
    for (int nt = 0; nt < 4; ++nt)
      bfv[nt] = *(const short8*)&Bs[(wn + nt * 16 + l15) * 32 + quad * 8];
#pragma unroll
    for (int mt = 0; mt < 4; ++mt)
#pragma unroll
      for (int nt = 0; nt < 4; ++nt)
        acc[mt][nt] = MFMA_BF16(af[mt], bfv[nt], acc[mt][nt]);
  }

  // ---- epilogue: wsel is block-uniform (n0 is a multiple of 128) ----
  const int wsel = n0 >> 10;                 // 0=Q 1=K 2=V
  const int b   = (m0 + wm) >> 10;           // 64-row subtile: single b
  const int i0l = (m0 + wm) & 1023;
  const int nl0 = (n0 & 1023) + wn;          // 64-aligned in [0,1024): single head
  const int h   = nl0 >> 6;
  const size_t bh = (size_t)(b * 16 + h);

  if (wsel == 0) {
#pragma unroll
    for (int mt = 0; mt < 4; ++mt)
#pragma unroll
      for (int nt = 0; nt < 4; ++nt)
#pragma unroll
        for (int r = 0; r < 4; ++r) {
          const int i = i0l + mt * 16 + quad * 4 + r;
          const int n = nl0 + nt * 16 + l15;
          float v = (acc[mt][nt][r] + bq[n]) * kScale;  // fold softmax scale
          Qh[(bh * 1024 + i) * 64 + (n & 63)] = f32_to_bf16(v);
        }
  } else if (wsel == 1) {
#pragma unroll
    for (int mt = 0; mt < 4; ++mt)
#pragma unroll
      for (int nt = 0; nt < 4; ++nt)
#pragma unroll
        for (int r = 0; r < 4; ++r) {
          const int i = i0l + mt * 16 + quad * 4 + r;
          const int n = nl0 + nt * 16 + l15;
          const int d = n & 63;
          float v = acc[mt][nt][r] + bk[n] + Er[(size_t)(4999 - i) * 64 + d];
          Kh[(bh * 1024 + i) * 64 + d] = f32_to_bf16(v);
        }
  } else {
    // V: transpose 64x64 wave subtile through LDS, store coalesced rows of Vth
    __syncthreads();                         // everyone done with As/Bs
    unsigned short* W = (unsigned short*)smem + (size_t)wave * 4608;  // 64x72
#pragma unroll
    for (int mt = 0; mt < 4; ++mt)
#pragma unroll
      for (int nt = 0; nt < 4; ++nt) {
        ushort4 pk;
        const int n = nl0 + nt * 16 + l15;
        pk.x = f32_to_bf16(acc[mt][nt][0] + bv[n]);
        pk.y = f32_to_bf16(acc[mt][nt][1] + bv[n]);
        pk.z = f32_to_bf16(acc[mt][nt][2] + bv[n]);
        pk.w = f32_to_bf16(acc[mt][nt][3] + bv[n]);
        // W[d][i] layout, stride 72: d = nt*16+l15, i = mt*16+quad*4+(0..3)
        *(ushort4*)&W[(size_t)(nt * 16 + l15) * 72 + mt * 16 + quad * 4] = pk;
      }
    __syncthreads();                         // W filled (also orders per-wave)
#pragma unroll
    for (int p = 0; p < 8; ++p) {
      const int u = p * 64 + lane;           // 512 x 16B units
      const int d = u >> 3, ch = (u & 7) * 8;
      short8 vv = *(const short8*)&W[(size_t)d * 72 + ch];
      *(short8*)&Vth[(bh * 64 + d) * 1024 + i0l + ch] = vv;
    }
  }
}

// ---------------- out GEMM  out[4096,1024] = Aoh @ Wo^T + b_o ----------------
// 128x64 tile -> 512 blocks (2/CU). 4 waves stacked in M (32 rows each).
__global__ __launch_bounds__(256)
void gemm_out(const unsigned short* __restrict__ A,   // 4096 x 1024
              const unsigned short* __restrict__ Bm,  // 1024 x 1024
              const float* __restrict__ bias,
              float* __restrict__ outf) {
  __shared__ unsigned short As[128 * 32];
  __shared__ unsigned short Bs[64 * 32];
  const int tid  = threadIdx.x;
  const int lane = tid & 63, wave = tid >> 6;
  const int quad = lane >> 4, l15 = lane & 15;
  const int m0 = blockIdx.y * 128, n0 = blockIdx.x * 64;
  const int K = 1024;

  const f32x4 vzero = {0.f, 0.f, 0.f, 0.f};
  f32x4 acc[2][4];
#pragma unroll
  for (int i = 0; i < 2; ++i)
#pragma unroll
    for (int j = 0; j < 4; ++j) acc[i][j] = vzero;

  for (int k0 = 0; k0 < K; k0 += 32) {
    __syncthreads();
#pragma unroll
    for (int r = 0; r < 2; ++r) {       // A: 512 units
      int u = r * 256 + tid;
      int row = u >> 2, col = (u & 3) * 8;
      gload_lds16(A + (size_t)(m0 + row) * K + k0 + col, (char*)As + (size_t)u * 16);
    }
    {                                   // B: 256 units (64 rows x 32)
      int u = tid;
      int row = u >> 2, col = (u & 3) * 8;
      gload_lds16(Bm + (size_t)(n0 + row) * K + k0 + col, (char*)Bs + (size_t)u * 16);
    }
    __syncthreads();

    short8 af[2], bfv[4];
#pragma unroll
    for (int mt = 0; mt < 2; ++mt)
      af[mt] = *(const short8*)&As[(wave * 32 + mt * 16 + l15) * 32 + quad * 8];
#pragma unroll
    for (int nt = 0; nt < 4; ++nt)
      bfv[nt] = *(const short8*)&Bs[(nt * 16 + l15) * 32 + quad * 8];
#pragma unroll
    for (int mt = 0; mt < 2; ++mt)
#pragma unroll
      for (int nt = 0; nt < 4; ++nt)
        acc[mt][nt] = MFMA_BF16(af[mt], bfv[nt], acc[mt][nt]);
  }

#pragma unroll
  for (int mt = 0; mt < 2; ++mt)
#pragma unroll
    for (int nt = 0; nt < 4; ++nt)
#pragma unroll
      for (int r = 0; r < 4; ++r) {
        const int gm = m0 + wave * 32 + mt * 16 + quad * 4 + r;
        const int gn = n0 + nt * 16 + l15;
        outf[(size_t)gm * 1024 + gn] = acc[mt][nt][r] + bias[gn];
      }
}

// ---------------- flash attention, LDS-staged K/V, prefetch ----------------
// grid (64 bh, 8 qblocks of 128), 256 threads. Wave owns 32 query rows.
// Q pre-scaled by log2(e)/8; no-max softmax (exp2 cannot overflow here).
// K/V tiles stored as two BK=32 halves -> 64B LDS rows (2-way bank alias, free).
__global__ __launch_bounds__(256)
void attn_kernel(const unsigned short* __restrict__ Q,
                 const unsigned short* __restrict__ Kp,
                 const unsigned short* __restrict__ Vt,
                 unsigned short* __restrict__ Ao) {
  __shared__ unsigned short Ks[2][2][64 * 32];  // [buf][half][key][32]
  __shared__ unsigned short Vs[2][2][64 * 32];  // [buf][half][d][32]
  __shared__ unsigned short Plds[4][32 * 72];   // per-wave P transpose
  const int tid  = threadIdx.x;
  const int lane = tid & 63, wave = tid >> 6;
  const int quad = lane >> 4, l15 = lane & 15;
  const int bh = blockIdx.x;
  const int qb = blockIdx.y;
  const size_t base  = (size_t)bh * (kL * 64);
  const size_t vbase = (size_t)bh * (64 * kL);
  const int i0 = qb * 128 + wave * 32;

  // Q fragments: 2 m-tiles x 2 k-steps, held in regs for whole kernel
  short8 qf[2][2];
#pragma unroll
  for (int mt = 0; mt < 2; ++mt)
#pragma unroll
    for (int ks = 0; ks < 2; ++ks)
      qf[mt][ks] = *(const short8*)
          &Q[base + (size_t)(i0 + mt * 16 + l15) * 64 + ks * 32 + quad * 8];

  // stage K/V tile kb into buffer buf. unit u in [0,512): LDS elem = u*8
  //  -> half = u>>8, row = (u>>2)&63, c = (u&3)*8   (lane-contiguous 16B)
  auto stage = [&](int buf, int kb) {
#pragma unroll
    for (int j = 0; j < 2; ++j) {
      int u = j * 256 + tid;
      int half = u >> 8, row = (u >> 2) & 63, c = (u & 3) * 8;
      gload_lds16(Kp + base + (size_t)(kb * 64 + row) * 64 + half * 32 + c,
                  (char*)&Ks[buf][0][0] + (size_t)u * 16);
      gload_lds16(Vt + vbase + (size_t)row * kL + kb * 64 + half * 32 + c,
                  (char*)&Vs[buf][0][0] + (size_t)u * 16);
    }
  };

  const f32x4 vzero = {0.f, 0.f, 0.f, 0.f};
  f32x4 of[2][4];
#pragma unroll
  for (int mt = 0; mt < 2; ++mt)
#pragma unroll
    for (int dt = 0; dt < 4; ++dt) of[mt][dt] = vzero;
  float lsum[2][4] = {{0.f, 0.f, 0.f, 0.f}, {0.f, 0.f, 0.f, 0.f}};

  unsigned short* Pw = Plds[wave];

  stage(0, 0);
  __syncthreads();   // drains vmcnt -> tile 0 visible

  for (int kb = 0; kb < 16; ++kb) {
    const int cur = kb & 1, nxt = cur ^ 1;
    if (kb < 15) stage(nxt, kb + 1);   // async; lands before end-of-iter barrier

    // ---- S = Q @ K'^T (64 keys) ----
    short8 kf[4][2];
#pragma unroll
    for (int nt = 0; nt < 4; ++nt)
#pragma unroll
      for (int ks = 0; ks < 2; ++ks)
        kf[nt][ks] = *(const short8*)&Ks[cur][ks][(nt * 16 + l15) * 32 + quad * 8];
    f32x4 sf[2][4];
#pragma unroll
    for (int mt = 0; mt < 2; ++mt)
#pragma unroll
      for (int nt = 0; nt < 4; ++nt) {
        sf[mt][nt] = MFMA_BF16(qf[mt][0], kf[nt][0], vzero);
        sf[mt][nt] = MFMA_BF16(qf[mt][1], kf[nt][1], sf[mt][nt]);
      }

    // ---- P = exp2(S); partial row sums; transpose via wave-private LDS ----
#pragma unroll
    for (int mt = 0; mt < 2; ++mt)
#pragma unroll
      for (int nt = 0; nt < 4; ++nt)
#pragma unroll
        for (int r = 0; r < 4; ++r) {
          float p = __builtin_amdgcn_exp2f(sf[mt][nt][r]);
          lsum[mt][r] += p;
          union { float f; uint32_t u; } c; c.f = p;
          Pw[(mt * 16 + quad * 4 + r) * 72 + nt * 16 + l15] =
              (unsigned short)((c.u + 0x8000u) >> 16);   // RN pack, 1 add
        }
    short8 pf[2][2];
#pragma unroll
    for (int mt = 0; mt < 2; ++mt)
#pragma unroll
      for (int ks = 0; ks < 2; ++ks)
        pf[mt][ks] = *(const short8*)&Pw[(mt * 16 + l15) * 72 + ks * 32 + quad * 8];

    // ---- O += P @ V ----
    short8 vf[4][2];
#pragma unroll
    for (int dt = 0; dt < 4; ++dt)
#pragma unroll
      for (int ks = 0; ks < 2; ++ks)
        vf[dt][ks] = *(const short8*)&Vs[cur][ks][(dt * 16 + l15) * 32 + quad * 8];
#pragma unroll
    for (int mt = 0; mt < 2; ++mt)
#pragma unroll
      for (int dt = 0; dt < 4; ++dt) {
        of[mt][dt] = MFMA_BF16(pf[mt][0], vf[dt][0], of[mt][dt]);
        of[mt][dt] = MFMA_BF16(pf[mt][1], vf[dt][1], of[mt][dt]);
      }

    __syncthreads();  // prefetch landed + all waves done with cur buffer
  }

  // ---- finish row sums across 16 lanes ----
#pragma unroll
  for (int mask = 1; mask < 16; mask <<= 1)
#pragma unroll
    for (int mt = 0; mt < 2; ++mt)
#pragma unroll
      for (int r = 0; r < 4; ++r)
        lsum[mt][r] += __shfl_xor(lsum[mt][r], mask);
  float rl[2][4];
#pragma unroll
  for (int mt = 0; mt < 2; ++mt)
#pragma unroll
    for (int r = 0; r < 4; ++r) rl[mt][r] = __builtin_amdgcn_rcpf(lsum[mt][r]);

  // ---- write Ao[b*L + i][h*64 + d] (bf16) ----
  const int b = bh >> 4, h = bh & 15;
#pragma unroll
  for (int mt = 0; mt < 2; ++mt)
#pragma unroll
    for (int dt = 0; dt < 4; ++dt)
#pragma unroll
      for (int r = 0; r < 4; ++r) {
        const int ig = i0 + mt * 16 + quad * 4 + r;
        float v = of[mt][dt][r] * rl[mt][r];
        Ao[((size_t)(b * 1024 + ig)) * 1024 + h * 64 + dt * 16 + l15] = f32_to_bf16(v);
      }
}

// ---------------------------------------------------------------------------
extern "C" void kernel_launch(void* const* d_in, const int* in_sizes, int n_in,
                              void* d_out, int out_size, void* d_ws, size_t ws_size,
                              hipStream_t stream) {
  const float* x   = (const float*)d_in[0];
  const float* W_q = (const float*)d_in[1];
  const float* b_q = (const float*)d_in[2];
  const float* W_k = (const float*)d_in[3];
  const float* b_k = (const float*)d_in[4];
  const float* W_v = (const float*)d_in[5];
  const float* b_v = (const float*)d_in[6];
  const float* W_o = (const float*)d_in[7];
  const float* b_o = (const float*)d_in[8];
  const float* Er  = (const float*)d_in[9];
  float* out = (float*)d_out;

  char* ws = (char*)d_ws;
  unsigned short* xb   = (unsigned short*)(ws + (size_t)0);          // 8 MB
  unsigned short* Wcat = (unsigned short*)(ws + ((size_t)8  << 20)); // 6 MB (Wq|Wk|Wv)
  unsigned short* Wob  = (unsigned short*)(ws + ((size_t)14 << 20)); // 2 MB
  unsigned short* Qh   = (unsigned short*)(ws + ((size_t)16 << 20)); // 8 MB [bh][i][d]
  unsigned short* Kh   = (unsigned short*)(ws + ((size_t)24 << 20)); // 8 MB [bh][i][d]
  unsigned short* Vth  = (unsigned short*)(ws + ((size_t)32 << 20)); // 8 MB [bh][d][i]
  unsigned short* Aoh  = (unsigned short*)(ws + ((size_t)40 << 20)); // 8 MB [b*L][D]

  cast_all<<<8192, 256, 0, stream>>>(x, W_q, W_k, W_v, W_o, xb, Wcat, Wob);

  gemm_qkv<<<dim3(24, 32), 256, 0, stream>>>(
      xb, Wcat, b_q, b_k, b_v, Er, Qh, Kh, Vth);

  attn_kernel<<<dim3(kB * kH, kL / 128), 256, 0, stream>>>(Qh, Kh, Vth, Aoh);

  gemm_out<<<dim3(16, 32), 256, 0, stream>>>(Aoh, Wob, b_o, out);
}

// Round 6
// 187.203 us; speedup vs baseline: 1.0248x; 1.0248x over previous
//
#include <hip/hip_runtime.h>
#include <cstdint>
#include <cstddef>

// ---------------------------------------------------------------------------
// RelativePositionMultiHeadAttention, B=4 L=1024 D=1024 H=16 dk=64
// Identity: BD[...,L-1:][b,h,i,j] = Q[b,h,i] . Er[4999-j]
//  => scores = Q @ (K + Er_flip)^T / 8  -> plain softmax attention.
// R6: GEMMs -> BK=64 two-plane LDS ([half][row][32]; frag rows stay 64B =
//     free 2-way alias), halving barrier drains; gemm_qkv LDS = exactly 32 KB
//     with V-transpose arena folded in (stride-64, one-time conflicts OK).
// ---------------------------------------------------------------------------

typedef __attribute__((ext_vector_type(8))) short short8;   // 8 x bf16 (4 VGPR)
typedef __attribute__((ext_vector_type(4))) float f32x4;    // 4 x f32

#define MFMA_BF16(a, b, c) __builtin_amdgcn_mfma_f32_16x16x32_bf16((a), (b), (c), 0, 0, 0)

constexpr int kB = 4, kL = 1024, kD = 1024, kH = 16;
constexpr int kBL = kB * kL;   // 4096
constexpr float kScale = 0.125f * 1.44269504088896340736f;  // log2(e)/sqrt(dk)

static __device__ __forceinline__ unsigned short f32_to_bf16(float f) {
  union { float f; uint32_t u; } c; c.f = f;
  uint32_t u = c.u + 0x7fffu + ((c.u >> 16) & 1u);  // RNE
  return (unsigned short)(u >> 16);
}

static __device__ __forceinline__ void gload_lds16(const void* g, void* l) {
  __builtin_amdgcn_global_load_lds(
      (const __attribute__((address_space(1))) void*)g,
      (__attribute__((address_space(3))) void*)l, 16, 0, 0);
}

// ---------------- single fused cast: x, Wq, Wk, Wv, Wo -> bf16 ----------------
__global__ __launch_bounds__(256)
void cast_all(const float* __restrict__ x,  const float* __restrict__ Wq,
              const float* __restrict__ Wk, const float* __restrict__ Wv,
              const float* __restrict__ Wo,
              unsigned short* __restrict__ xb, unsigned short* __restrict__ Wcat,
              unsigned short* __restrict__ Wob) {
  int i = blockIdx.x * blockDim.x + threadIdx.x;
  const float* src;
  ushort4* dst;
  int off;
  if (i < 1048576) {
    src = x; dst = reinterpret_cast<ushort4*>(xb); off = i;
  } else {
    int j = i - 1048576;
    int seg = j >> 18;          // 0..3
    off = j & 262143;
    if (seg == 0)      { src = Wq; dst = reinterpret_cast<ushort4*>(Wcat); }
    else if (seg == 1) { src = Wk; dst = reinterpret_cast<ushort4*>(Wcat) + 262144; }
    else if (seg == 2) { src = Wv; dst = reinterpret_cast<ushort4*>(Wcat) + 524288; }
    else               { src = Wo; dst = reinterpret_cast<ushort4*>(Wob); }
  }
  float4 v = reinterpret_cast<const float4*>(src)[off];
  ushort4 o;
  o.x = f32_to_bf16(v.x); o.y = f32_to_bf16(v.y);
  o.z = f32_to_bf16(v.z); o.w = f32_to_bf16(v.w);
  dst[off] = o;
}

// ---------------- fused QKV GEMM  [4096 x 3072] = xb @ Wcat^T ----------------
// 128x128 tile, BK=64 (two 32-planes), 4 waves (2x2 of 64x64).
// C/D: col=lane&15, row=quad*4+reg. LDS = 32 KB exactly; V epilogue reuses it.
__global__ __launch_bounds__(256)
void gemm_qkv(const unsigned short* __restrict__ A,   // 4096 x 1024 bf16
              const unsigned short* __restrict__ Bm,  // 3072 x 1024 bf16
              const float* __restrict__ bq, const float* __restrict__ bk,
              const float* __restrict__ bv,
              const float* __restrict__ Er,           // 5000x64 f32
              unsigned short* __restrict__ Qh, unsigned short* __restrict__ Kh,
              unsigned short* __restrict__ Vth) {
  __shared__ __align__(16) char smem[32768];
  unsigned short* As = (unsigned short*)smem;            // [2][128][32]
  unsigned short* Bs = (unsigned short*)(smem + 16384);  // [2][128][32]
  const int tid  = threadIdx.x;
  const int lane = tid & 63, wave = tid >> 6;
  const int quad = lane >> 4, l15 = lane & 15;
  const int m0 = blockIdx.y * 128, n0 = blockIdx.x * 128;
  const int wm = (wave >> 1) * 64, wn = (wave & 1) * 64;
  const int K = 1024;

  const f32x4 vzero = {0.f, 0.f, 0.f, 0.f};
  f32x4 acc[4][4];
#pragma unroll
  for (int i = 0; i < 4; ++i)
#pragma unroll
    for (int j = 0; j < 4; ++j) acc[i][j] = vzero;

  for (int k0 = 0; k0 < K; k0 += 64) {
    __syncthreads();
#pragma unroll
    for (int j = 0; j < 4; ++j) {
      // unit u in [0,1024): lds elems u*8 = half*4096 + row*32 + (u&3)*8
      int u = j * 256 + tid;
      int half = u >> 9, row = (u >> 2) & 127, c = (u & 3) * 8 + half * 32;
      gload_lds16(A  + (size_t)(m0 + row) * K + k0 + c, (char*)As + (size_t)u * 16);
      gload_lds16(Bm + (size_t)(n0 + row) * K + k0 + c, (char*)Bs + (size_t)u * 16);
    }
    __syncthreads();

#pragma unroll
    for (int ks = 0; ks < 2; ++ks) {
      short8 af[4], bfv[4];
#pragma unroll
      for (int mt = 0; mt < 4; ++mt)
        af[mt] = *(const short8*)&As[ks * 4096 + (wm + mt * 16 + l15) * 32 + quad * 8];
#pragma unroll
      for (int nt = 0; nt < 4; ++nt)
        bfv[nt] = *(const short8*)&Bs[ks * 4096 + (wn + nt * 16 + l15) * 32 + quad * 8];
#pragma unroll
      for (int mt = 0; mt < 4; ++mt)
#pragma unroll
        for (int nt = 0; nt < 4; ++nt)
          acc[mt][nt] = MFMA_BF16(af[mt], bfv[nt], acc[mt][nt]);
    }
  }

  // ---- epilogue: wsel is block-uniform (n0 is a multiple of 128) ----
  const int wsel = n0 >> 10;                 // 0=Q 1=K 2=V
  const int b   = (m0 + wm) >> 10;           // 64-row subtile: single b
  const int i0l = (m0 + wm) & 1023;
  const int nl0 = (n0 & 1023) + wn;          // 64-aligned in [0,1024): single head
  const int h   = nl0 >> 6;
  const size_t bh = (size_t)(b * 16 + h);

  if (wsel == 0) {
#pragma unroll
    for (int mt = 0; mt < 4; ++mt)
#pragma unroll
      for (int nt = 0; nt < 4; ++nt)
#pragma unroll
        for (int r = 0; r < 4; ++r) {
          const int i = i0l + mt * 16 + quad * 4 + r;
          const int n = nl0 + nt * 16 + l15;
          float v = (acc[mt][nt][r] + bq[n]) * kScale;  // fold softmax scale
          Qh[(bh * 1024 + i) * 64 + (n & 63)] = f32_to_bf16(v);
        }
  } else if (wsel == 1) {
#pragma unroll
    for (int mt = 0; mt < 4; ++mt)
#pragma unroll
      for (int nt = 0; nt < 4; ++nt)
#pragma unroll
        for (int r = 0; r < 4; ++r) {
          const int i = i0l + mt * 16 + quad * 4 + r;
          const int n = nl0 + nt * 16 + l15;
          const int d = n & 63;
          float v = acc[mt][nt][r] + bk[n] + Er[(size_t)(4999 - i) * 64 + d];
          Kh[(bh * 1024 + i) * 64 + d] = f32_to_bf16(v);
        }
  } else {
    // V: transpose 64x64 wave subtile through wave-private 8 KB of the arena.
    __syncthreads();                         // all waves done reading As/Bs
    unsigned short* W = (unsigned short*)smem + (size_t)wave * 4096;  // 64x64
#pragma unroll
    for (int mt = 0; mt < 4; ++mt)
#pragma unroll
      for (int nt = 0; nt < 4; ++nt) {
        ushort4 pk;
        const int n = nl0 + nt * 16 + l15;
        pk.x = f32_to_bf16(acc[mt][nt][0] + bv[n]);
        pk.y = f32_to_bf16(acc[mt][nt][1] + bv[n]);
        pk.z = f32_to_bf16(acc[mt][nt][2] + bv[n]);
        pk.w = f32_to_bf16(acc[mt][nt][3] + bv[n]);
        // W[d][i]: d = nt*16+l15, i = mt*16+quad*4+(0..3)  (one-time conflicts OK)
        *(ushort4*)&W[(size_t)(nt * 16 + l15) * 64 + mt * 16 + quad * 4] = pk;
      }
    // wave-private region: no barrier needed (compiler inserts lgkmcnt wait)
#pragma unroll
    for (int p = 0; p < 8; ++p) {
      const int u = p * 64 + lane;           // 512 x 16B units, wave-local
      const int d = u >> 3, ch = (u & 7) * 8;
      short8 vv = *(const short8*)&W[(size_t)d * 64 + ch];
      *(short8*)&Vth[(bh * 64 + d) * 1024 + i0l + ch] = vv;
    }
  }
}

// ---------------- out GEMM  out[4096,1024] = Aoh @ Wo^T + b_o ----------------
// 128x64 tile, BK=64 two-plane -> 512 blocks. 4 waves stacked in M.
__global__ __launch_bounds__(256)
void gemm_out(const unsigned short* __restrict__ A,   // 4096 x 1024
              const unsigned short* __restrict__ Bm,  // 1024 x 1024
              const float* __restrict__ bias,
              float* __restrict__ outf) {
  __shared__ unsigned short As[2][128 * 32];  // 16 KB
  __shared__ unsigned short Bs[2][64 * 32];   // 8 KB
  const int tid  = threadIdx.x;
  const int lane = tid & 63, wave = tid >> 6;
  const int quad = lane >> 4, l15 = lane & 15;
  const int m0 = blockIdx.y * 128, n0 = blockIdx.x * 64;
  const int K = 1024;

  const f32x4 vzero = {0.f, 0.f, 0.f, 0.f};
  f32x4 acc[2][4];
#pragma unroll
  for (int i = 0; i < 2; ++i)
#pragma unroll
    for (int j = 0; j < 4; ++j) acc[i][j] = vzero;

  for (int k0 = 0; k0 < K; k0 += 64) {
    __syncthreads();
#pragma unroll
    for (int j = 0; j < 4; ++j) {       // A: 1024 units
      int u = j * 256 + tid;
      int half = u >> 9, row = (u >> 2) & 127, c = (u & 3) * 8 + half * 32;
      gload_lds16(A + (size_t)(m0 + row) * K + k0 + c, (char*)&As[0][0] + (size_t)u * 16);
    }
#pragma unroll
    for (int j = 0; j < 2; ++j) {       // B: 512 units
      int u = j * 256 + tid;
      int half = u >> 8, row = (u >> 2) & 63, c = (u & 3) * 8 + half * 32;
      gload_lds16(Bm + (size_t)(n0 + row) * K + k0 + c, (char*)&Bs[0][0] + (size_t)u * 16);
    }
    __syncthreads();

#pragma unroll
    for (int ks = 0; ks < 2; ++ks) {
      short8 af[2], bfv[4];
#pragma unroll
      for (int mt = 0; mt < 2; ++mt)
        af[mt] = *(const short8*)&As[ks][(wave * 32 + mt * 16 + l15) * 32 + quad * 8];
#pragma unroll
      for (int nt = 0; nt < 4; ++nt)
        bfv[nt] = *(const short8*)&Bs[ks][(nt * 16 + l15) * 32 + quad * 8];
#pragma unroll
      for (int mt = 0; mt < 2; ++mt)
#pragma unroll
        for (int nt = 0; nt < 4; ++nt)
          acc[mt][nt] = MFMA_BF16(af[mt], bfv[nt], acc[mt][nt]);
    }
  }

#pragma unroll
  for (int mt = 0; mt < 2; ++mt)
#pragma unroll
    for (int nt = 0; nt < 4; ++nt)
#pragma unroll
      for (int r = 0; r < 4; ++r) {
        const int gm = m0 + wave * 32 + mt * 16 + quad * 4 + r;
        const int gn = n0 + nt * 16 + l15;
        outf[(size_t)gm * 1024 + gn] = acc[mt][nt][r] + bias[gn];
      }
}

// ---------------- flash attention, LDS-staged K/V, prefetch ----------------
// grid (64 bh, 8 qblocks of 128), 256 threads. Wave owns 32 query rows.
// Q pre-scaled by log2(e)/8; no-max softmax (exp2 cannot overflow here).
__global__ __launch_bounds__(256)
void attn_kernel(const unsigned short* __restrict__ Q,
                 const unsigned short* __restrict__ Kp,
                 const unsigned short* __restrict__ Vt,
                 unsigned short* __restrict__ Ao) {
  __shared__ unsigned short Ks[2][2][64 * 32];  // [buf][half][key][32]
  __shared__ unsigned short Vs[2][2][64 * 32];  // [buf][half][d][32]
  __shared__ unsigned short Plds[4][32 * 72];   // per-wave P transpose
  const int tid  = threadIdx.x;
  const int lane = tid & 63, wave = tid >> 6;
  const int quad = lane >> 4, l15 = lane & 15;
  const int bh = blockIdx.x;
  const int qb = blockIdx.y;
  const size_t base  = (size_t)bh * (kL * 64);
  const size_t vbase = (size_t)bh * (64 * kL);
  const int i0 = qb * 128 + wave * 32;

  short8 qf[2][2];
#pragma unroll
  for (int mt = 0; mt < 2; ++mt)
#pragma unroll
    for (int ks = 0; ks < 2; ++ks)
      qf[mt][ks] = *(const short8*)
          &Q[base + (size_t)(i0 + mt * 16 + l15) * 64 + ks * 32 + quad * 8];

  auto stage = [&](int buf, int kb) {
#pragma unroll
    for (int j = 0; j < 2; ++j) {
      int u = j * 256 + tid;
      int half = u >> 8, row = (u >> 2) & 63, c = (u & 3) * 8;
      gload_lds16(Kp + base + (size_t)(kb * 64 + row) * 64 + half * 32 + c,
                  (char*)&Ks[buf][0][0] + (size_t)u * 16);
      gload_lds16(Vt + vbase + (size_t)row * kL + kb * 64 + half * 32 + c,
                  (char*)&Vs[buf][0][0] + (size_t)u * 16);
    }
  };

  const f32x4 vzero = {0.f, 0.f, 0.f, 0.f};
  f32x4 of[2][4];
#pragma unroll
  for (int mt = 0; mt < 2; ++mt)
#pragma unroll
    for (int dt = 0; dt < 4; ++dt) of[mt][dt] = vzero;
  float lsum[2][4] = {{0.f, 0.f, 0.f, 0.f}, {0.f, 0.f, 0.f, 0.f}};

  unsigned short* Pw = Plds[wave];

  stage(0, 0);
  __syncthreads();

  for (int kb = 0; kb < 16; ++kb) {
    const int cur = kb & 1, nxt = cur ^ 1;
    if (kb < 15) stage(nxt, kb + 1);

    short8 kf[4][2];
#pragma unroll
    for (int nt = 0; nt < 4; ++nt)
#pragma unroll
      for (int ks = 0; ks < 2; ++ks)
        kf[nt][ks] = *(const short8*)&Ks[cur][ks][(nt * 16 + l15) * 32 + quad * 8];
    f32x4 sf[2][4];
#pragma unroll
    for (int mt = 0; mt < 2; ++mt)
#pragma unroll
      for (int nt = 0; nt < 4; ++nt) {
        sf[mt][nt] = MFMA_BF16(qf[mt][0], kf[nt][0], vzero);
        sf[mt][nt] = MFMA_BF16(qf[mt][1], kf[nt][1], sf[mt][nt]);
      }

#pragma unroll
    for (int mt = 0; mt < 2; ++mt)
#pragma unroll
      for (int nt = 0; nt < 4; ++nt)
#pragma unroll
        for (int r = 0; r < 4; ++r) {
          float p = __builtin_amdgcn_exp2f(sf[mt][nt][r]);
          lsum[mt][r] += p;
          union { float f; uint32_t u; } c; c.f = p;
          Pw[(mt * 16 + quad * 4 + r) * 72 + nt * 16 + l15] =
              (unsigned short)((c.u + 0x8000u) >> 16);
        }
    short8 pf[2][2];
#pragma unroll
    for (int mt = 0; mt < 2; ++mt)
#pragma unroll
      for (int ks = 0; ks < 2; ++ks)
        pf[mt][ks] = *(const short8*)&Pw[(mt * 16 + l15) * 72 + ks * 32 + quad * 8];

    short8 vf[4][2];
#pragma unroll
    for (int dt = 0; dt < 4; ++dt)
#pragma unroll
      for (int ks = 0; ks < 2; ++ks)
        vf[dt][ks] = *(const short8*)&Vs[cur][ks][(dt * 16 + l15) * 32 + quad * 8];
#pragma unroll
    for (int mt = 0; mt < 2; ++mt)
#pragma unroll
      for (int dt = 0; dt < 4; ++dt) {
        of[mt][dt] = MFMA_BF16(pf[mt][0], vf[dt][0], of[mt][dt]);
        of[mt][dt] = MFMA_BF16(pf[mt][1], vf[dt][1], of[mt][dt]);
      }

    __syncthreads();
  }

#pragma unroll
  for (int mask = 1; mask < 16; mask <<= 1)
#pragma unroll
    for (int mt = 0; mt < 2; ++mt)
#pragma unroll
      for (int r = 0; r < 4; ++r)
        lsum[mt][r] += __shfl_xor(lsum[mt][r], mask);
  float rl[2][4];
#pragma unroll
  for (int mt = 0; mt < 2; ++mt)
#pragma unroll
    for (int r = 0; r < 4; ++r) rl[mt][r] = __builtin_amdgcn_rcpf(lsum[mt][r]);

  const int b = bh >> 4, h = bh & 15;
#pragma unroll
  for (int mt = 0; mt < 2; ++mt)
#pragma unroll
    for (int dt = 0; dt < 4; ++dt)
#pragma unroll
      for (int r = 0; r < 4; ++r) {
        const int ig = i0 + mt * 16 + quad * 4 + r;
        float v = of[mt][dt][r] * rl[mt][r];
        Ao[((size_t)(b * 1024 + ig)) * 1024 + h * 64 + dt * 16 + l15] = f32_to_bf16(v);
      }
}

// ---------------------------------------------------------------------------
extern "C" void kernel_launch(void* const* d_in, const int* in_sizes, int n_in,
                              void* d_out, int out_size, void* d_ws, size_t ws_size,
                              hipStream_t stream) {
  const float* x   = (const float*)d_in[0];
  const float* W_q = (const float*)d_in[1];
  const float* b_q = (const float*)d_in[2];
  const float* W_k = (const float*)d_in[3];
  const float* b_k = (const float*)d_in[4];
  const float* W_v = (const float*)d_in[5];
  const float* b_v = (const float*)d_in[6];
  const float* W_o = (const float*)d_in[7];
  const float* b_o = (const float*)d_in[8];
  const float* Er  = (const float*)d_in[9];
  float* out = (float*)d_out;

  char* ws = (char*)d_ws;
  unsigned short* xb   = (unsigned short*)(ws + (size_t)0);          // 8 MB
  unsigned short* Wcat = (unsigned short*)(ws + ((size_t)8  << 20)); // 6 MB (Wq|Wk|Wv)
  unsigned short* Wob  = (unsigned short*)(ws + ((size_t)14 << 20)); // 2 MB
  unsigned short* Qh   = (unsigned short*)(ws + ((size_t)16 << 20)); // 8 MB [bh][i][d]
  unsigned short* Kh   = (unsigned short*)(ws + ((size_t)24 << 20)); // 8 MB [bh][i][d]
  unsigned short* Vth  = (unsigned short*)(ws + ((size_t)32 << 20)); // 8 MB [bh][d][i]
  unsigned short* Aoh  = (unsigned short*)(ws + ((size_t)40 << 20)); // 8 MB [b*L][D]

  cast_all<<<8192, 256, 0, stream>>>(x, W_q, W_k, W_v, W_o, xb, Wcat, Wob);

  gemm_qkv<<<dim3(24, 32), 256, 0, stream>>>(
      xb, Wcat, b_q, b_k, b_v, Er, Qh, Kh, Vth);

  attn_kernel<<<dim3(kB * kH, kL / 128), 256, 0, stream>>>(Qh, Kh, Vth, Aoh);

  gemm_out<<<dim3(16, 32), 256, 0, stream>>>(Aoh, Wob, b_o, out);
}